// Round 4
// baseline (223.694 us; speedup 1.0000x reference)
//
#include <hip/hip_runtime.h>

typedef __attribute__((ext_vector_type(8))) __bf16 bf16x8;
typedef __attribute__((ext_vector_type(4))) float f32x4;

#define DI __device__ __forceinline__

// float -> bf16 bits, RNE
DI unsigned short f2bf(float x) {
  unsigned u = __float_as_uint(x);
  u += 0x7fffu + ((u >> 16) & 1u);
  return (unsigned short)(u >> 16);
}

DI bf16x8 cvt8(f32x4 lo, f32x4 hi) {
  bf16x8 r;
  r[0] = (__bf16)lo.x; r[1] = (__bf16)lo.y; r[2] = (__bf16)lo.z; r[3] = (__bf16)lo.w;
  r[4] = (__bf16)hi.x; r[5] = (__bf16)hi.y; r[6] = (__bf16)hi.z; r[7] = (__bf16)hi.w;
  return r;
}

DI float tanh_fast(float x) {
  float ax = fabsf(x);
  float e = __expf(-2.0f * ax);
  float t = (1.0f - e) / (1.0f + e);
  return x < 0.0f ? -t : t;
}

// async global->LDS, 16 B per lane; LDS dst = wave-uniform base + lane*16.
DI void glds16(const void* gptr, void* lptr) {
  __builtin_amdgcn_global_load_lds(
      (const __attribute__((address_space(1))) unsigned int*)gptr,
      (__attribute__((address_space(3))) unsigned int*)lptr, 16, 0, 0);
}

// ---------------------------------------------------------------------------
// Kernel 0: W [512(k),256(n)] fp32 -> Wt [256(n),512(k)] bf16 (B^T layout).
// ---------------------------------------------------------------------------
__global__ void k_wt(const float* __restrict__ W, unsigned short* __restrict__ Wt) {
  int n = blockIdx.x;
  int t = threadIdx.x;     // 0..127
  int k = t * 4;
  ushort4 v;
  v.x = f2bf(W[(k + 0) * 256 + n]);
  v.y = f2bf(W[(k + 1) * 256 + n]);
  v.z = f2bf(W[(k + 2) * 256 + n]);
  v.w = f2bf(W[(k + 3) * 256 + n]);
  *(ushort4*)&Wt[n * 512 + k] = v;
}

// ---------------------------------------------------------------------------
// Kernel 1: projection GEMM. M=65536, K=512, N=256. Block 128x256, 512 thr,
// 8 waves as 4(row)x2(col), wave-tile 32x128 (acc 64 f32/lane).
// A (fp32, the HBM payload): DIRECT global->VGPR stream, cvt to bf16 in-reg.
//   Waves own disjoint 32-row groups => A read once from HBM (2x L1-filtered
//   overlap between the wn=0/1 waves of a row group).
// B (Wt, 256 KB, L2-hot): LDS double-buffer, BK=64 windows (2x32 KB), staged
//   one window AHEAD via global_load_lds => the per-window barrier drains a
//   long-since-landed L2 fetch, not a fresh HBM burst.
// Bs tiled layout (glds is flat lane*16): addr(n,c)= (n>>3)*1024 + (n&7)*128
//   + ((c ^ (n&7))<<4)  [c = 16B chunk 0..7]; XOR spreads frag reads to 2-way.
// ---------------------------------------------------------------------------
__global__ __launch_bounds__(512, 4) void k_proj(
    const float* __restrict__ Alt, const float* __restrict__ Art,
    const unsigned short* __restrict__ Wt, const float* __restrict__ diag,
    unsigned short* __restrict__ Olt, unsigned short* __restrict__ Ort) {
  __shared__ __align__(16) unsigned short Bs[2][256 * 64];   // 2 x 32 KB

  int bx = blockIdx.x;              // 0..511
  bool is_lt = bx < 256;
  int m0 = (is_lt ? bx : bx - 256) * 128;
  const float* A = (is_lt ? Alt : Art) + (size_t)m0 * 512;
  unsigned short* O = (is_lt ? Olt : Ort) + (size_t)m0 * 256;

  int tid  = threadIdx.x;
  int lane = tid & 63;
  int wid  = tid >> 6;              // 0..7
  int wm   = wid >> 1;              // 0..3 -> 32-row group
  int wn   = wid & 1;               // 0..1 -> 128-col group
  int l15  = lane & 15;
  int quad = lane >> 4;
  int lr8  = lane >> 3;
  int s8   = lane & 7;

  const char* Wb = (const char*)Wt;
  // per-lane glds source offset inside an 8-row group (row stride 1024 B)
  int bsrc = lr8 * 1024 + ((s8 ^ lr8) << 4);

  // per-lane A row pointers (2 mt-frags)
  const float* ap0 = A + (size_t)(wm * 32 + 0 * 16 + l15) * 512 + quad * 8;
  const float* ap1 = A + (size_t)(wm * 32 + 1 * 16 + l15) * 512 + quad * 8;

  f32x4 zero = {0.0f, 0.0f, 0.0f, 0.0f};
  f32x4 acc[2][8];
#pragma unroll
  for (int i = 0; i < 2; i++)
#pragma unroll
    for (int j = 0; j < 8; j++) acc[i][j] = zero;

  // ---- prologue: stage window 0 into Bs[0]
#pragma unroll
  for (int i = 0; i < 4; i++) {
    int j = wid * 4 + i;            // 8-row group j covers rows j*8..j*8+7
    glds16(Wb + (size_t)j * 8192 + bsrc, (char*)Bs[0] + j * 1024);
  }
  __syncthreads();

  for (int kw = 0; kw < 8; kw++) {
    int cur = kw & 1;
    if (kw < 7) {                   // stage NEXT window into the other buffer
#pragma unroll
      for (int i = 0; i < 4; i++) {
        int j = wid * 4 + i;
        glds16(Wb + (size_t)j * 8192 + (kw + 1) * 128 + bsrc,
               (char*)Bs[cur ^ 1] + j * 1024);
      }
    }
    const char* Bc = (const char*)Bs[cur];
#pragma unroll
    for (int ks = 0; ks < 2; ks++) {
      bf16x8 a[2], b[8];
      {
        f32x4 lo0 = *(const f32x4*)(ap0 + kw * 64 + ks * 32);
        f32x4 hi0 = *(const f32x4*)(ap0 + kw * 64 + ks * 32 + 4);
        f32x4 lo1 = *(const f32x4*)(ap1 + kw * 64 + ks * 32);
        f32x4 hi1 = *(const f32x4*)(ap1 + kw * 64 + ks * 32 + 4);
        a[0] = cvt8(lo0, hi0);
        a[1] = cvt8(lo1, hi1);
      }
#pragma unroll
      for (int nt = 0; nt < 8; nt++) {
        int n = wn * 128 + nt * 16 + l15;
        int c = ks * 4 + quad;
        b[nt] = *(const bf16x8*)(Bc + (n >> 3) * 1024 + (n & 7) * 128 +
                                 ((c ^ (n & 7)) << 4));
      }
#pragma unroll
      for (int mt = 0; mt < 2; mt++)
#pragma unroll
        for (int nt = 0; nt < 8; nt++)
          acc[mt][nt] = __builtin_amdgcn_mfma_f32_16x16x32_bf16(a[mt], b[nt], acc[mt][nt], 0, 0, 0);
    }
    __syncthreads();
  }

  // Epilogue: tanh, diag scale (lt only), bf16 store.
  float dscale[8];
#pragma unroll
  for (int nt = 0; nt < 8; nt++)
    dscale[nt] = is_lt ? diag[wn * 128 + nt * 16 + l15] : 1.0f;

#pragma unroll
  for (int mt = 0; mt < 2; mt++) {
#pragma unroll
    for (int r = 0; r < 4; r++) {
      int row = wm * 32 + mt * 16 + quad * 4 + r;
#pragma unroll
      for (int nt = 0; nt < 8; nt++) {
        int col = wn * 128 + nt * 16 + l15;
        O[(size_t)row * 256 + col] = f2bf(tanh_fast(acc[mt][nt][r]) * dscale[nt]);
      }
    }
  }
}

// ---------------------------------------------------------------------------
// Kernel 2: per-batch logits (lt_b @ rt_b^T, K=256) + fused exact softmax.
// Block 64(L) x 512(R), 8 waves (wid = 64-col group), wave-tile 64x64.
// Lt tile (32 KB): staged in LDS ONCE (tiled+XOR layout), single barrier.
// Rt: DIRECT global->VGPR stream (L2-hot; each wave reads only its own 64-R
// slice once => no redundancy). K-loop fully unrolled, ZERO barriers.
// Ls addr(r,c)= (r>>3)*4096 + (c>>3)*1024 + (r&7)*128 + (((c&7)^(r&7))<<4).
// ---------------------------------------------------------------------------
__global__ __launch_bounds__(512, 4) void k_attn(
    const unsigned short* __restrict__ Lt, const unsigned short* __restrict__ Rt,
    float* __restrict__ Out) {
  __shared__ __align__(16) unsigned short Ls[64 * 256];   // 32 KB
  __shared__ float red[8][64];
  __shared__ float rowv[64];

  int bx = blockIdx.x;                       // 0..511
  int b  = (bx & 7) * 8 + ((bx >> 3) & 7);   // batch, XCD-co-located
  int l0 = (bx >> 6) * 64;
  const char* Lb = (const char*)(Lt + ((size_t)b * 512 + l0) * 256);
  const unsigned short* Rb = Rt + (size_t)b * 512 * 256;
  float* Ob = Out + ((size_t)b * 512 + l0) * 512;

  int tid  = threadIdx.x;
  int lane = tid & 63;
  int wid  = tid >> 6;              // 0..7 -> 64-col group
  int l15  = lane & 15;
  int quad = lane >> 4;
  int lr8  = lane >> 3;
  int s8   = lane & 7;

  // ---- stage Lt tile once: 32 glds (4/wave). inst j: rg=j>>2 rows, rq=j&3
  // k-quarter (128 B). LDS flat j*1024 + lane*16 == tiled layout above.
#pragma unroll
  for (int i = 0; i < 4; i++) {
    int j = wid * 4 + i;
    int rg = j >> 2, rq = j & 3;
    glds16(Lb + (size_t)(rg * 8 + lr8) * 512 + rq * 128 + ((s8 ^ lr8) << 4),
           (char*)Ls + j * 1024);
  }
  __syncthreads();

  // Rt per-lane row pointers (4 nt-frags, this wave's 64-R slice)
  const unsigned short* bp[4];
#pragma unroll
  for (int nt = 0; nt < 4; nt++)
    bp[nt] = Rb + (size_t)(wid * 64 + nt * 16 + l15) * 256 + quad * 8;

  f32x4 zero = {0.0f, 0.0f, 0.0f, 0.0f};
  f32x4 acc[4][4];
#pragma unroll
  for (int i = 0; i < 4; i++)
#pragma unroll
    for (int j = 0; j < 4; j++) acc[i][j] = zero;

#pragma unroll
  for (int ks = 0; ks < 8; ks++) {
    bf16x8 a[4], bb[4];
#pragma unroll
    for (int nt = 0; nt < 4; nt++)
      bb[nt] = *(const bf16x8*)(bp[nt] + ks * 32);
#pragma unroll
    for (int mt = 0; mt < 4; mt++) {
      int r = mt * 16 + l15;
      int c = ks * 4 + quad;
      a[mt] = *(const bf16x8*)((const char*)Ls + (r >> 3) * 4096 + (c >> 3) * 1024 +
                               (r & 7) * 128 + (((c & 7) ^ (r & 7)) << 4));
    }
#pragma unroll
    for (int mt = 0; mt < 4; mt++)
#pragma unroll
      for (int nt = 0; nt < 4; nt++)
        acc[mt][nt] = __builtin_amdgcn_mfma_f32_16x16x32_bf16(a[mt], bb[nt], acc[mt][nt], 0, 0, 0);
  }

  // -------- softmax over the 512-wide row (8 col-groups) --------
#pragma unroll
  for (int mt = 0; mt < 4; mt++) {
#pragma unroll
    for (int r = 0; r < 4; r++) {
      float m = fmaxf(fmaxf(acc[mt][0][r], acc[mt][1][r]),
                      fmaxf(acc[mt][2][r], acc[mt][3][r]));
      m = fmaxf(m, __shfl_xor(m, 1));
      m = fmaxf(m, __shfl_xor(m, 2));
      m = fmaxf(m, __shfl_xor(m, 4));
      m = fmaxf(m, __shfl_xor(m, 8));
      if (l15 == 0) red[wid][mt * 16 + quad * 4 + r] = m;
    }
  }
  __syncthreads();
  if (tid < 64) {
    float m = red[0][tid];
#pragma unroll
    for (int w = 1; w < 8; w++) m = fmaxf(m, red[w][tid]);
    rowv[tid] = m;
  }
  __syncthreads();

#pragma unroll
  for (int mt = 0; mt < 4; mt++) {
#pragma unroll
    for (int r = 0; r < 4; r++) {
      float base = rowv[mt * 16 + quad * 4 + r];
      float s = 0.0f;
#pragma unroll
      for (int nt = 0; nt < 4; nt++) {
        float e = __expf(acc[mt][nt][r] - base);
        acc[mt][nt][r] = e;
        s += e;
      }
      s += __shfl_xor(s, 1);
      s += __shfl_xor(s, 2);
      s += __shfl_xor(s, 4);
      s += __shfl_xor(s, 8);
      if (l15 == 0) red[wid][mt * 16 + quad * 4 + r] = s;
    }
  }
  __syncthreads();
  if (tid < 64) {
    float s = red[0][tid];
#pragma unroll
    for (int w = 1; w < 8; w++) s += red[w][tid];
    rowv[tid] = 1.0f / s;
  }
  __syncthreads();

#pragma unroll
  for (int mt = 0; mt < 4; mt++) {
#pragma unroll
    for (int r = 0; r < 4; r++) {
      int row = mt * 16 + quad * 4 + r;
      float inv = rowv[row];
#pragma unroll
      for (int nt = 0; nt < 4; nt++) {
        int col = wid * 64 + nt * 16 + l15;
        Ob[(size_t)row * 512 + col] = acc[mt][nt][r] * inv;
      }
    }
  }
}

// ---------------------------------------------------------------------------
extern "C" void kernel_launch(void* const* d_in, const int* in_sizes, int n_in,
                              void* d_out, int out_size, void* d_ws, size_t ws_size,
                              hipStream_t stream) {
  const float* lstm_lt = (const float*)d_in[0];   // (64,512,512)
  const float* lstm_rt = (const float*)d_in[1];   // (64,512,512)
  const float* W       = (const float*)d_in[2];   // (512,256)
  const float* diag    = (const float*)d_in[3];   // (256)
  float* out = (float*)d_out;                     // (64,512,512)

  // Workspace: Wt bf16 [256,512] | lt bf16 [32768,256] | rt bf16 [32768,256]
  unsigned short* Wt  = (unsigned short*)d_ws;
  unsigned short* Olt = (unsigned short*)((char*)d_ws + (size_t)256 * 512 * 2);
  unsigned short* Ort = Olt + (size_t)32768 * 256;

  k_wt<<<dim3(256), dim3(128), 0, stream>>>(W, Wt);
  k_proj<<<dim3(512), dim3(512), 0, stream>>>(lstm_lt, lstm_rt, Wt, diag, Olt, Ort);
  k_attn<<<dim3(512), dim3(512), 0, stream>>>(Olt, Ort, out);
}